// Round 1
// baseline (55.609 us; speedup 1.0000x reference)
//
#include <hip/hip_runtime.h>
#include <math.h>

#define N 2048
#define D 128
#define NUM_CLASSES 64
#define JSPLIT 8
#define TI 64
#define TJ 128
#define DP 132   // padded LDS row stride (floats): 16B-aligned rows, conflict-free
#define NTHREADS 512

__global__ __launch_bounds__(256) void norms_kernel(const float* __restrict__ q,
                                                    float* __restrict__ norms) {
    int i = blockIdx.x * blockDim.x + threadIdx.x;
    if (i >= N) return;
    const float4* qr = reinterpret_cast<const float4*>(q) + i * (D / 4);
    float s = 0.f;
#pragma unroll
    for (int c = 0; c < D / 4; ++c) {
        float4 v = qr[c];
        s += v.x * v.x + v.y * v.y + v.z * v.z + v.w * v.w;
    }
    norms[i] = s;
}

__global__ __launch_bounds__(NTHREADS) void pair_kernel(
    const float* __restrict__ q, const int* __restrict__ tgt,
    const float* __restrict__ norms,
    float* __restrict__ wpv, float* __restrict__ wpr, float* __restrict__ wnv) {
    __shared__ float Qi[TI * DP];
    __shared__ float Qj[TJ * DP];
    __shared__ float sni[TI];
    __shared__ int   sti[TI];
    __shared__ float snj[TJ];
    __shared__ int   stj[TJ];

    const int ib = blockIdx.x / JSPLIT;
    const int s  = blockIdx.x % JSPLIT;
    const int i0 = ib * TI;
    const int j0 = s * (N / JSPLIT);
    const int tid = threadIdx.x;

    // stage the i-tile (64 rows x 128 floats) as float4
    for (int t = tid; t < TI * (D / 4); t += NTHREADS) {
        int r = t >> 5, c = t & 31;
        float4 v = reinterpret_cast<const float4*>(q)[(i0 + r) * (D / 4) + c];
        *reinterpret_cast<float4*>(&Qi[r * DP + c * 4]) = v;
    }
    if (tid < TI) { sni[tid] = norms[i0 + tid]; sti[tid] = tgt[i0 + tid]; }

    const int a = tid >> 5;  // 0..15 -> i group of 4
    const int b = tid & 31;  // j lane

    float bpv[4], bpr[4], bnv[4];
    int bpi[4];
#pragma unroll
    for (int m = 0; m < 4; ++m) {
        bpv[m] = -INFINITY; bpr[m] = 0.f; bnv[m] = INFINITY; bpi[m] = 0x7fffffff;
    }

    for (int jt = 0; jt < (N / JSPLIT) / TJ; ++jt) {
        const int jb = j0 + jt * TJ;
        __syncthreads();  // protect Qj (and first-iter Qi) before overwrite/use
        for (int t = tid; t < TJ * (D / 4); t += NTHREADS) {
            int r = t >> 5, c = t & 31;
            float4 v = reinterpret_cast<const float4*>(q)[(jb + r) * (D / 4) + c];
            *reinterpret_cast<float4*>(&Qj[r * DP + c * 4]) = v;
        }
        if (tid < TJ) { snj[tid] = norms[jb + tid]; stj[tid] = tgt[jb + tid]; }
        __syncthreads();

        float acc[4][4];
#pragma unroll
        for (int m = 0; m < 4; ++m)
#pragma unroll
            for (int n = 0; n < 4; ++n) acc[m][n] = 0.f;

#pragma unroll 8
        for (int d0 = 0; d0 < D; d0 += 4) {
            float4 av[4], bv[4];
#pragma unroll
            for (int m = 0; m < 4; ++m)
                av[m] = *reinterpret_cast<const float4*>(&Qi[(a * 4 + m) * DP + d0]);
#pragma unroll
            for (int n = 0; n < 4; ++n)
                bv[n] = *reinterpret_cast<const float4*>(&Qj[(b + 32 * n) * DP + d0]);
#pragma unroll
            for (int m = 0; m < 4; ++m)
#pragma unroll
                for (int n = 0; n < 4; ++n)
                    acc[m][n] += av[m].x * bv[n].x + av[m].y * bv[n].y +
                                 av[m].z * bv[n].z + av[m].w * bv[n].w;
        }

        // candidate updates (jnp semantics: diag->-inf, same->dist, else->0.0; argmax,
        // then the VALUE used is the raw distance at the argmax index)
#pragma unroll
        for (int n = 0; n < 4; ++n) {
            const int jl = b + 32 * n;
            const int jg = jb + jl;
            const float nj = snj[jl];
            const int tj = stj[jl];
#pragma unroll
            for (int m = 0; m < 4; ++m) {
                const int ig = i0 + a * 4 + m;
                const float dist = sni[a * 4 + m] + nj - 2.f * acc[m][n];
                const bool diag = (ig == jg);
                const bool same = (sti[a * 4 + m] == tj);
                const float pmv = diag ? -INFINITY : (same ? dist : 0.f);
                if (pmv > bpv[m] || (pmv == bpv[m] && jg < bpi[m])) {
                    bpv[m] = pmv; bpr[m] = dist; bpi[m] = jg;
                }
                const float nmv = (same || diag) ? INFINITY : dist;
                bnv[m] = fminf(bnv[m], nmv);
            }
        }
    }

    // reduce across the 32 j-lanes (masks <=16 keep lanes within 32-halves of the wave)
#pragma unroll
    for (int mask = 16; mask >= 1; mask >>= 1) {
#pragma unroll
        for (int m = 0; m < 4; ++m) {
            float opv = __shfl_xor(bpv[m], mask);
            float opr = __shfl_xor(bpr[m], mask);
            int   opi = __shfl_xor(bpi[m], mask);
            float onv = __shfl_xor(bnv[m], mask);
            if (opv > bpv[m] || (opv == bpv[m] && opi < bpi[m])) {
                bpv[m] = opv; bpr[m] = opr; bpi[m] = opi;
            }
            bnv[m] = fminf(bnv[m], onv);
        }
    }
    if (b == 0) {
#pragma unroll
        for (int m = 0; m < 4; ++m) {
            const int ig = i0 + a * 4 + m;
            wpv[ig * JSPLIT + s] = bpv[m];
            wpr[ig * JSPLIT + s] = bpr[m];
            wnv[ig * JSPLIT + s] = bnv[m];
        }
    }
}

__global__ __launch_bounds__(256) void finalize_kernel(
    const float* __restrict__ wpv, const float* __restrict__ wpr,
    const float* __restrict__ wnv, float* __restrict__ out) {
    __shared__ float red[256];
    const int t = threadIdx.x;
    float sum = 0.f;
    for (int r = t; r < N; r += 256) {
        float pv = -INFINITY, pr2 = 0.f, nv = INFINITY;
        // ascending slice order + strict '>' == first-index tie-break
        for (int s2 = 0; s2 < JSPLIT; ++s2) {
            float v = wpv[r * JSPLIT + s2];
            if (v > pv) { pv = v; pr2 = wpr[r * JSPLIT + s2]; }
            nv = fminf(nv, wnv[r * JSPLIT + s2]);
        }
        sum += fmaxf(0.f, 1.0f - pr2 + nv);
    }
    red[t] = sum;
    __syncthreads();
    for (int s2 = 128; s2 > 0; s2 >>= 1) {
        if (t < s2) red[t] += red[t + s2];
        __syncthreads();
    }
    if (t == 0) out[0] = red[0] / (float)N;
}

extern "C" void kernel_launch(void* const* d_in, const int* in_sizes, int n_in,
                              void* d_out, int out_size, void* d_ws, size_t ws_size,
                              hipStream_t stream) {
    const float* q  = (const float*)d_in[0];
    const int* tgt  = (const int*)d_in[1];
    float* ws = (float*)d_ws;
    float* norms = ws;                 // N
    float* wpv = norms + N;            // N*JSPLIT
    float* wpr = wpv + N * JSPLIT;     // N*JSPLIT
    float* wnv = wpr + N * JSPLIT;     // N*JSPLIT
    float* out = (float*)d_out;

    hipLaunchKernelGGL(norms_kernel, dim3(N / 256), dim3(256), 0, stream, q, norms);
    hipLaunchKernelGGL(pair_kernel, dim3((N / TI) * JSPLIT), dim3(NTHREADS), 0, stream,
                       q, tgt, norms, wpv, wpr, wnv);
    hipLaunchKernelGGL(finalize_kernel, dim3(1), dim3(256), 0, stream, wpv, wpr, wnv, out);
}

// Round 2
// 49.682 us; speedup vs baseline: 1.1193x; 1.1193x over previous
//
#include <hip/hip_runtime.h>
#include <math.h>
#include <stdint.h>

#define N 2048
#define D 128
#define JSPLIT 32
#define BM 128           // i-rows per block = 4 waves * 32
#define BN 64            // j-slice width = N / JSPLIT
#define PAIR_THREADS 256

typedef __attribute__((ext_vector_type(8))) short bf16x8;
typedef __attribute__((ext_vector_type(4))) float f32x4;

// round-to-nearest-even fp32 -> bf16, also returns the bf16 value as fp32
__device__ __forceinline__ ushort f2bf_rne(float x, float* back) {
    uint32_t u = __float_as_uint(x);
    uint32_t r = u + 0x7FFFu + ((u >> 16) & 1u);
    ushort h = (ushort)(r >> 16);
    *back = __uint_as_float(((uint32_t)h) << 16);
    return h;
}

// one wave per 2 rows: convert Q -> (H, L) bf16 split + exact fp32 row norms
__global__ __launch_bounds__(64) void prep_kernel(const float* __restrict__ q,
                                                  ushort* __restrict__ H,
                                                  ushort* __restrict__ L,
                                                  float* __restrict__ norms) {
    const int lane = threadIdx.x;
    const int r = blockIdx.x * 2 + (lane >> 5);
    const int c4 = lane & 31;
    float4 v = reinterpret_cast<const float4*>(q)[r * (D / 4) + c4];
    float xs[4] = {v.x, v.y, v.z, v.w};
    ushort hs[4], ls[4];
    float nsum = 0.f;
#pragma unroll
    for (int e = 0; e < 4; ++e) {
        float x = xs[e];
        nsum = fmaf(x, x, nsum);
        float hb, dummy;
        hs[e] = f2bf_rne(x, &hb);
        ls[e] = f2bf_rne(x - hb, &dummy);
    }
    reinterpret_cast<ushort4*>(H)[r * (D / 4) + c4] = make_ushort4(hs[0], hs[1], hs[2], hs[3]);
    reinterpret_cast<ushort4*>(L)[r * (D / 4) + c4] = make_ushort4(ls[0], ls[1], ls[2], ls[3]);
#pragma unroll
    for (int m = 16; m >= 1; m >>= 1) nsum += __shfl_xor(nsum, m);
    if ((lane & 31) == 0) norms[r] = nsum;
}

__global__ __launch_bounds__(PAIR_THREADS, 2) void pair_kernel(
    const ushort* __restrict__ H, const ushort* __restrict__ L,
    const float* __restrict__ norms, const int* __restrict__ tgt,
    float* __restrict__ wpv, int* __restrict__ wpi,
    float* __restrict__ wnv, int* __restrict__ wni) {
    __shared__ ushort HJ[BN * D];  // XOR-swizzled rows (256 B/row)
    __shared__ ushort LJ[BN * D];
    __shared__ float snj[BN];
    __shared__ int stj[BN];

    const int ib = blockIdx.x / JSPLIT;
    const int s = blockIdx.x % JSPLIT;
    const int i0 = ib * BM;
    const int j0 = s * BN;
    const int tid = threadIdx.x;
    const int w = tid >> 6;
    const int lane = tid & 63;
    const int lr = lane & 15;  // A/B fragment row, C col
    const int h = lane >> 4;   // 0..3

    // ---- stage j-tile into LDS, swizzled: byte ^= (row&7)<<4 (16B granules) ----
    for (int c = tid; c < BN * 16; c += PAIR_THREADS) {
        int row = c >> 4, col = c & 15;
        int boff = row * 256 + ((col * 16) ^ ((row & 7) << 4));
        uint4 vh = reinterpret_cast<const uint4*>(H)[(j0 + row) * (D / 8) + col];
        *reinterpret_cast<uint4*>((char*)HJ + boff) = vh;
        uint4 vl = reinterpret_cast<const uint4*>(L)[(j0 + row) * (D / 8) + col];
        *reinterpret_cast<uint4*>((char*)LJ + boff) = vl;
    }
    if (tid < BN) {
        snj[tid] = norms[j0 + tid];
        stj[tid] = tgt[j0 + tid];
    }

    // ---- A fragments: 2 row-tiles * 4 k-steps, H and L, held in registers ----
    const int rowbase = i0 + w * 32;
    bf16x8 AH[2][4], AL[2][4];
#pragma unroll
    for (int rt = 0; rt < 2; ++rt)
#pragma unroll
        for (int kk = 0; kk < 4; ++kk) {
            int r = rowbase + rt * 16 + lr;
            AH[rt][kk] = *reinterpret_cast<const bf16x8*>(&H[r * D + kk * 32 + h * 8]);
            AL[rt][kk] = *reinterpret_cast<const bf16x8*>(&L[r * D + kk * 32 + h * 8]);
        }
    // norms/targets for this lane's C rows: row = rt*16 + h*4 + m
    float ni[2][4];
    int ti[2][4];
#pragma unroll
    for (int rt = 0; rt < 2; ++rt)
#pragma unroll
        for (int m = 0; m < 4; ++m) {
            int r = rowbase + rt * 16 + h * 4 + m;
            ni[rt][m] = norms[r];
            ti[rt][m] = tgt[r];
        }

    float bpv[2][4], bnv[2][4];
    int bpi[2][4], bni[2][4];
#pragma unroll
    for (int rt = 0; rt < 2; ++rt)
#pragma unroll
        for (int m = 0; m < 4; ++m) {
            bpv[rt][m] = -INFINITY; bpi[rt][m] = 0;
            bnv[rt][m] = INFINITY;  bni[rt][m] = 0;
        }

    __syncthreads();

    for (int ct = 0; ct < BN / 16; ++ct) {
        const int brow = ct * 16 + lr;
        const int bswz = (brow & 7) << 4;
        const char* hbase = (const char*)HJ + brow * 256;
        const char* lbase = (const char*)LJ + brow * 256;
        bf16x8 BH[4], BL[4];
#pragma unroll
        for (int kk = 0; kk < 4; ++kk) {
            int off = (kk * 64 + h * 16) ^ bswz;
            BH[kk] = *reinterpret_cast<const bf16x8*>(hbase + off);
            BL[kk] = *reinterpret_cast<const bf16x8*>(lbase + off);
        }
        f32x4 acc[2];
        acc[0] = (f32x4){0.f, 0.f, 0.f, 0.f};
        acc[1] = (f32x4){0.f, 0.f, 0.f, 0.f};
#pragma unroll
        for (int rt = 0; rt < 2; ++rt) {
#pragma unroll
            for (int kk = 0; kk < 4; ++kk)
                acc[rt] = __builtin_amdgcn_mfma_f32_16x16x32_bf16(AH[rt][kk], BH[kk], acc[rt], 0, 0, 0);
#pragma unroll
            for (int kk = 0; kk < 4; ++kk)
                acc[rt] = __builtin_amdgcn_mfma_f32_16x16x32_bf16(AH[rt][kk], BL[kk], acc[rt], 0, 0, 0);
#pragma unroll
            for (int kk = 0; kk < 4; ++kk)
                acc[rt] = __builtin_amdgcn_mfma_f32_16x16x32_bf16(AL[rt][kk], BH[kk], acc[rt], 0, 0, 0);
#pragma unroll
            for (int kk = 0; kk < 4; ++kk)
                acc[rt] = __builtin_amdgcn_mfma_f32_16x16x32_bf16(AL[rt][kk], BL[kk], acc[rt], 0, 0, 0);
        }
        const int jl = ct * 16 + lr;
        const int jg = j0 + jl;
        const float njc = snj[jl];
        const int tjc = stj[jl];
#pragma unroll
        for (int rt = 0; rt < 2; ++rt)
#pragma unroll
            for (int m = 0; m < 4; ++m) {
                const float dist = fmaf(-2.f, acc[rt][m], ni[rt][m] + njc);
                const bool same = (ti[rt][m] == tjc);
                const float pmv = same ? dist : 0.f;
                if (pmv > bpv[rt][m]) { bpv[rt][m] = pmv; bpi[rt][m] = jg; }
                const float nmv = same ? INFINITY : dist;
                if (nmv < bnv[rt][m]) { bnv[rt][m] = nmv; bni[rt][m] = jg; }
            }
    }

    // reduce across the 16 lanes (lr) that share each C row; xor masks stay in-group
#pragma unroll
    for (int mask = 1; mask <= 8; mask <<= 1) {
#pragma unroll
        for (int rt = 0; rt < 2; ++rt)
#pragma unroll
            for (int m = 0; m < 4; ++m) {
                float ov = __shfl_xor(bpv[rt][m], mask);
                int oi = __shfl_xor(bpi[rt][m], mask);
                if (ov > bpv[rt][m] || (ov == bpv[rt][m] && oi < bpi[rt][m])) {
                    bpv[rt][m] = ov; bpi[rt][m] = oi;
                }
                float onv = __shfl_xor(bnv[rt][m], mask);
                int oni = __shfl_xor(bni[rt][m], mask);
                if (onv < bnv[rt][m] || (onv == bnv[rt][m] && oni < bni[rt][m])) {
                    bnv[rt][m] = onv; bni[rt][m] = oni;
                }
            }
    }
    if (lr == 0) {
#pragma unroll
        for (int rt = 0; rt < 2; ++rt)
#pragma unroll
            for (int m = 0; m < 4; ++m) {
                int r = rowbase + rt * 16 + h * 4 + m;
                int idx = r * JSPLIT + s;
                wpv[idx] = bpv[rt][m]; wpi[idx] = bpi[rt][m];
                wnv[idx] = bnv[rt][m]; wni[idx] = bni[rt][m];
            }
    }
}

// merge slice partials, recompute selected distances EXACTLY in fp32, block-sum
__global__ __launch_bounds__(256) void finalize_kernel(
    const float* __restrict__ q, const float* __restrict__ wpv, const int* __restrict__ wpi,
    const float* __restrict__ wnv, const int* __restrict__ wni, float* __restrict__ bpart) {
    __shared__ float red[256];
    const int i = blockIdx.x * 256 + threadIdx.x;
    float pv = -INFINITY; int pi = 0;
    float nv = INFINITY;  int nidx = 0;
    for (int s = 0; s < JSPLIT; ++s) {
        float v = wpv[i * JSPLIT + s];
        if (v > pv) { pv = v; pi = wpi[i * JSPLIT + s]; }
        float u = wnv[i * JSPLIT + s];
        if (u < nv) { nv = u; nidx = wni[i * JSPLIT + s]; }
    }
    const float4* q4 = reinterpret_cast<const float4*>(q);
    float dp = 0.f, dn = 0.f;
#pragma unroll 4
    for (int c = 0; c < D / 4; ++c) {
        float4 a = q4[i * (D / 4) + c];
        float4 p = q4[pi * (D / 4) + c];
        float4 g = q4[nidx * (D / 4) + c];
        dp += (a.x - p.x) * (a.x - p.x) + (a.y - p.y) * (a.y - p.y) +
              (a.z - p.z) * (a.z - p.z) + (a.w - p.w) * (a.w - p.w);
        dn += (a.x - g.x) * (a.x - g.x) + (a.y - g.y) * (a.y - g.y) +
              (a.z - g.z) * (a.z - g.z) + (a.w - g.w) * (a.w - g.w);
    }
    red[threadIdx.x] = fmaxf(0.f, 1.0f - dp + dn);
    __syncthreads();
    for (int s2 = 128; s2 > 0; s2 >>= 1) {
        if (threadIdx.x < s2) red[threadIdx.x] += red[threadIdx.x + s2];
        __syncthreads();
    }
    if (threadIdx.x == 0) bpart[blockIdx.x] = red[0];
}

__global__ __launch_bounds__(64) void reduce_kernel(const float* __restrict__ bpart,
                                                    float* __restrict__ out) {
    float v = (threadIdx.x < 8) ? bpart[threadIdx.x] : 0.f;
#pragma unroll
    for (int m = 1; m <= 4; m <<= 1) v += __shfl_xor(v, m);
    if (threadIdx.x == 0) out[0] = v / (float)N;
}

extern "C" void kernel_launch(void* const* d_in, const int* in_sizes, int n_in,
                              void* d_out, int out_size, void* d_ws, size_t ws_size,
                              hipStream_t stream) {
    const float* q = (const float*)d_in[0];
    const int* tgt = (const int*)d_in[1];

    ushort* H = (ushort*)d_ws;              // N*D bf16
    ushort* L = H + N * D;                  // N*D bf16
    float* norms = (float*)(L + N * D);     // N
    float* wpv = norms + N;                 // N*JSPLIT
    int* wpi = (int*)(wpv + N * JSPLIT);    // N*JSPLIT
    float* wnv = (float*)(wpi + N * JSPLIT);
    int* wni = (int*)(wnv + N * JSPLIT);
    float* bpart = (float*)(wni + N * JSPLIT);  // 8
    float* out = (float*)d_out;

    hipLaunchKernelGGL(prep_kernel, dim3(N / 2), dim3(64), 0, stream, q, H, L, norms);
    hipLaunchKernelGGL(pair_kernel, dim3((N / BM) * JSPLIT), dim3(PAIR_THREADS), 0, stream,
                       H, L, norms, tgt, wpv, wpi, wnv, wni);
    hipLaunchKernelGGL(finalize_kernel, dim3(8), dim3(256), 0, stream,
                       q, wpv, wpi, wnv, wni, bpart);
    hipLaunchKernelGGL(reduce_kernel, dim3(1), dim3(64), 0, stream, bpart, out);
}

// Round 3
// 38.105 us; speedup vs baseline: 1.4594x; 1.3038x over previous
//
#include <hip/hip_runtime.h>
#include <math.h>
#include <stdint.h>

#define N 2048
#define D 128
#define JSPLIT 32
#define BM 128           // i-rows per block = 4 waves * 32
#define BN 64            // j-slice width = N / JSPLIT
#define PAIR_THREADS 256

typedef __attribute__((ext_vector_type(8))) short bf16x8;
typedef __attribute__((ext_vector_type(4))) float f32x4;

// round-to-nearest-even fp32 -> bf16, also returns the bf16 value as fp32
__device__ __forceinline__ ushort f2bf_rne(float x, float* back) {
    uint32_t u = __float_as_uint(x);
    uint32_t r = u + 0x7FFFu + ((u >> 16) & 1u);
    ushort h = (ushort)(r >> 16);
    *back = __uint_as_float(((uint32_t)h) << 16);
    return h;
}

// one wave per 2 rows: convert Q -> (H, L) bf16 split + exact fp32 row norms
__global__ __launch_bounds__(64) void prep_kernel(const float* __restrict__ q,
                                                  ushort* __restrict__ H,
                                                  ushort* __restrict__ L,
                                                  float* __restrict__ norms) {
    const int lane = threadIdx.x;
    const int r = blockIdx.x * 2 + (lane >> 5);
    const int c4 = lane & 31;
    float4 v = reinterpret_cast<const float4*>(q)[r * (D / 4) + c4];
    float xs[4] = {v.x, v.y, v.z, v.w};
    ushort hs[4], ls[4];
    float nsum = 0.f;
#pragma unroll
    for (int e = 0; e < 4; ++e) {
        float x = xs[e];
        nsum = fmaf(x, x, nsum);
        float hb, dummy;
        hs[e] = f2bf_rne(x, &hb);
        ls[e] = f2bf_rne(x - hb, &dummy);
    }
    reinterpret_cast<ushort4*>(H)[r * (D / 4) + c4] = make_ushort4(hs[0], hs[1], hs[2], hs[3]);
    reinterpret_cast<ushort4*>(L)[r * (D / 4) + c4] = make_ushort4(ls[0], ls[1], ls[2], ls[3]);
#pragma unroll
    for (int m = 16; m >= 1; m >>= 1) nsum += __shfl_xor(nsum, m);
    if ((lane & 31) == 0) norms[r] = nsum;
}

__global__ __launch_bounds__(PAIR_THREADS, 2) void pair_kernel(
    const ushort* __restrict__ H, const ushort* __restrict__ L,
    const float* __restrict__ norms, const int* __restrict__ tgt,
    float* __restrict__ wpv, int* __restrict__ wpi,
    float* __restrict__ wnv, int* __restrict__ wni) {
    __shared__ ushort HJ[BN * D];  // XOR-swizzled rows (256 B/row)
    __shared__ ushort LJ[BN * D];
    __shared__ float snj[BN];
    __shared__ int stj[BN];

    const int ib = blockIdx.x / JSPLIT;
    const int s = blockIdx.x % JSPLIT;
    const int i0 = ib * BM;
    const int j0 = s * BN;
    const int tid = threadIdx.x;
    const int w = tid >> 6;
    const int lane = tid & 63;
    const int lr = lane & 15;  // A/B fragment row, C col
    const int h = lane >> 4;   // 0..3

    // ---- stage j-tile into LDS, swizzled: byte ^= (row&7)<<4 (16B granules) ----
    for (int c = tid; c < BN * 16; c += PAIR_THREADS) {
        int row = c >> 4, col = c & 15;
        int boff = row * 256 + ((col * 16) ^ ((row & 7) << 4));
        uint4 vh = reinterpret_cast<const uint4*>(H)[(j0 + row) * (D / 8) + col];
        *reinterpret_cast<uint4*>((char*)HJ + boff) = vh;
        uint4 vl = reinterpret_cast<const uint4*>(L)[(j0 + row) * (D / 8) + col];
        *reinterpret_cast<uint4*>((char*)LJ + boff) = vl;
    }
    if (tid < BN) {
        snj[tid] = norms[j0 + tid];
        stj[tid] = tgt[j0 + tid];
    }

    // ---- A fragments: 2 row-tiles * 4 k-steps, H and L, held in registers ----
    const int rowbase = i0 + w * 32;
    bf16x8 AH[2][4], AL[2][4];
#pragma unroll
    for (int rt = 0; rt < 2; ++rt)
#pragma unroll
        for (int kk = 0; kk < 4; ++kk) {
            int r = rowbase + rt * 16 + lr;
            AH[rt][kk] = *reinterpret_cast<const bf16x8*>(&H[r * D + kk * 32 + h * 8]);
            AL[rt][kk] = *reinterpret_cast<const bf16x8*>(&L[r * D + kk * 32 + h * 8]);
        }
    // norms/targets for this lane's C rows: row = rt*16 + h*4 + m
    float ni[2][4];
    int ti[2][4];
#pragma unroll
    for (int rt = 0; rt < 2; ++rt)
#pragma unroll
        for (int m = 0; m < 4; ++m) {
            int r = rowbase + rt * 16 + h * 4 + m;
            ni[rt][m] = norms[r];
            ti[rt][m] = tgt[r];
        }

    float bpv[2][4], bnv[2][4];
    int bpi[2][4], bni[2][4];
#pragma unroll
    for (int rt = 0; rt < 2; ++rt)
#pragma unroll
        for (int m = 0; m < 4; ++m) {
            bpv[rt][m] = -INFINITY; bpi[rt][m] = 0;
            bnv[rt][m] = INFINITY;  bni[rt][m] = 0;
        }

    __syncthreads();

    for (int ct = 0; ct < BN / 16; ++ct) {
        const int brow = ct * 16 + lr;
        const int bswz = (brow & 7) << 4;
        const char* hbase = (const char*)HJ + brow * 256;
        const char* lbase = (const char*)LJ + brow * 256;
        bf16x8 BH[4], BL[4];
#pragma unroll
        for (int kk = 0; kk < 4; ++kk) {
            int off = (kk * 64 + h * 16) ^ bswz;
            BH[kk] = *reinterpret_cast<const bf16x8*>(hbase + off);
            BL[kk] = *reinterpret_cast<const bf16x8*>(lbase + off);
        }
        f32x4 acc[2];
        acc[0] = (f32x4){0.f, 0.f, 0.f, 0.f};
        acc[1] = (f32x4){0.f, 0.f, 0.f, 0.f};
#pragma unroll
        for (int rt = 0; rt < 2; ++rt) {
#pragma unroll
            for (int kk = 0; kk < 4; ++kk)
                acc[rt] = __builtin_amdgcn_mfma_f32_16x16x32_bf16(AH[rt][kk], BH[kk], acc[rt], 0, 0, 0);
#pragma unroll
            for (int kk = 0; kk < 4; ++kk)
                acc[rt] = __builtin_amdgcn_mfma_f32_16x16x32_bf16(AH[rt][kk], BL[kk], acc[rt], 0, 0, 0);
#pragma unroll
            for (int kk = 0; kk < 4; ++kk)
                acc[rt] = __builtin_amdgcn_mfma_f32_16x16x32_bf16(AL[rt][kk], BH[kk], acc[rt], 0, 0, 0);
#pragma unroll
            for (int kk = 0; kk < 4; ++kk)
                acc[rt] = __builtin_amdgcn_mfma_f32_16x16x32_bf16(AL[rt][kk], BL[kk], acc[rt], 0, 0, 0);
        }
        const int jl = ct * 16 + lr;
        const int jg = j0 + jl;
        const float njc = snj[jl];
        const int tjc = stj[jl];
#pragma unroll
        for (int rt = 0; rt < 2; ++rt)
#pragma unroll
            for (int m = 0; m < 4; ++m) {
                const int ig = rowbase + rt * 16 + h * 4 + m;
                const float dist = fmaf(-2.f, acc[rt][m], ni[rt][m] + njc);
                const bool same = (ti[rt][m] == tjc);
                const bool diag = (ig == jg);
                const float pmv = diag ? -INFINITY : (same ? dist : 0.f);
                if (pmv > bpv[rt][m]) { bpv[rt][m] = pmv; bpi[rt][m] = jg; }
                const float nmv = (same || diag) ? INFINITY : dist;
                if (nmv < bnv[rt][m]) { bnv[rt][m] = nmv; bni[rt][m] = jg; }
            }
    }

    // reduce across the 16 lanes (lr) that share each C row; xor masks stay in-group
#pragma unroll
    for (int mask = 1; mask <= 8; mask <<= 1) {
#pragma unroll
        for (int rt = 0; rt < 2; ++rt)
#pragma unroll
            for (int m = 0; m < 4; ++m) {
                float ov = __shfl_xor(bpv[rt][m], mask);
                int oi = __shfl_xor(bpi[rt][m], mask);
                if (ov > bpv[rt][m] || (ov == bpv[rt][m] && oi < bpi[rt][m])) {
                    bpv[rt][m] = ov; bpi[rt][m] = oi;
                }
                float onv = __shfl_xor(bnv[rt][m], mask);
                int oni = __shfl_xor(bni[rt][m], mask);
                if (onv < bnv[rt][m] || (onv == bnv[rt][m] && oni < bni[rt][m])) {
                    bnv[rt][m] = onv; bni[rt][m] = oni;
                }
            }
    }
    if (lr == 0) {
#pragma unroll
        for (int rt = 0; rt < 2; ++rt)
#pragma unroll
            for (int m = 0; m < 4; ++m) {
                int r = rowbase + rt * 16 + h * 4 + m;
                int idx = r * JSPLIT + s;
                wpv[idx] = bpv[rt][m]; wpi[idx] = bpi[rt][m];
                wnv[idx] = bnv[rt][m]; wni[idx] = bni[rt][m];
            }
    }
}

// wave-per-row: merge slice partials lane-parallel, then coalesced exact recompute
__global__ __launch_bounds__(256) void finalize_kernel(
    const float* __restrict__ q, const float* __restrict__ wpv, const int* __restrict__ wpi,
    const float* __restrict__ wnv, const int* __restrict__ wni, float* __restrict__ bpart) {
    __shared__ float red[4];
    const int wave = threadIdx.x >> 6;
    const int lane = threadIdx.x & 63;
    const int l = lane & 31;
    const float2* q2 = reinterpret_cast<const float2*>(q);
    float lsum = 0.f;
#pragma unroll
    for (int r = 0; r < 8; ++r) {
        const int i = blockIdx.x * 32 + wave * 8 + r;
        // lane-parallel slice merge (both 32-halves duplicate -> identical results)
        float pv = wpv[i * JSPLIT + l];
        int pi = wpi[i * JSPLIT + l];
        float nv = wnv[i * JSPLIT + l];
        int ng = wni[i * JSPLIT + l];
#pragma unroll
        for (int mask = 1; mask <= 16; mask <<= 1) {
            float opv = __shfl_xor(pv, mask);
            int opi = __shfl_xor(pi, mask);
            if (opv > pv || (opv == pv && opi < pi)) { pv = opv; pi = opi; }
            float onv = __shfl_xor(nv, mask);
            int oni = __shfl_xor(ng, mask);
            if (onv < nv || (onv == nv && oni < ng)) { nv = onv; ng = oni; }
        }
        // exact fp32 recompute, coalesced: 64 lanes x float2 = one 512B row
        float2 a = q2[i * (D / 2) + lane];
        float2 p = q2[pi * (D / 2) + lane];
        float2 g = q2[ng * (D / 2) + lane];
        float dp = (a.x - p.x) * (a.x - p.x) + (a.y - p.y) * (a.y - p.y);
        float dn = (a.x - g.x) * (a.x - g.x) + (a.y - g.y) * (a.y - g.y);
#pragma unroll
        for (int mask = 1; mask <= 32; mask <<= 1) {
            dp += __shfl_xor(dp, mask);
            dn += __shfl_xor(dn, mask);
        }
        if (lane == 0) lsum += fmaxf(0.f, 1.0f - dp + dn);
    }
    if (lane == 0) red[wave] = lsum;
    __syncthreads();
    if (threadIdx.x == 0)
        bpart[blockIdx.x] = red[0] + red[1] + red[2] + red[3];
}

__global__ __launch_bounds__(64) void reduce_kernel(const float* __restrict__ bpart,
                                                    float* __restrict__ out) {
    float v = bpart[threadIdx.x];  // 64 partials, one per finalize block
#pragma unroll
    for (int m = 1; m <= 32; m <<= 1) v += __shfl_xor(v, m);
    if (threadIdx.x == 0) out[0] = v / (float)N;
}

extern "C" void kernel_launch(void* const* d_in, const int* in_sizes, int n_in,
                              void* d_out, int out_size, void* d_ws, size_t ws_size,
                              hipStream_t stream) {
    const float* q = (const float*)d_in[0];
    const int* tgt = (const int*)d_in[1];

    ushort* H = (ushort*)d_ws;              // N*D bf16
    ushort* L = H + N * D;                  // N*D bf16
    float* norms = (float*)(L + N * D);     // N
    float* wpv = norms + N;                 // N*JSPLIT
    int* wpi = (int*)(wpv + N * JSPLIT);    // N*JSPLIT
    float* wnv = (float*)(wpi + N * JSPLIT);
    int* wni = (int*)(wnv + N * JSPLIT);
    float* bpart = (float*)(wni + N * JSPLIT);  // 64
    float* out = (float*)d_out;

    hipLaunchKernelGGL(prep_kernel, dim3(N / 2), dim3(64), 0, stream, q, H, L, norms);
    hipLaunchKernelGGL(pair_kernel, dim3((N / BM) * JSPLIT), dim3(PAIR_THREADS), 0, stream,
                       H, L, norms, tgt, wpv, wpi, wnv, wni);
    hipLaunchKernelGGL(finalize_kernel, dim3(64), dim3(256), 0, stream,
                       q, wpv, wpi, wnv, wni, bpart);
    hipLaunchKernelGGL(reduce_kernel, dim3(1), dim3(64), 0, stream, bpart, out);
}